// Round 8
// baseline (430.704 us; speedup 1.0000x reference)
//
#include <hip/hip_runtime.h>
#include <math.h>

#define CCH 128
#define HH 64
#define WW 64
#define SHD 17
#define NSHIFT (SHD*SHD)   // 289

// ---- workspace layout ----
// float-index offsets:
#define OFF_KEY    0                         // 256 u32 monotone sim-max keys
#define OFF_NORM   256                       // 16 f  (grd sumsq)
#define OFF_ENERGY 272                       // 16*64*64 f
#define OFF_SCALE  65808                     // 16*289 f
#define ZERO_BYTES 263232                    // keys + norm + energy
// byte offsets:
#define OFF_SATP_B 294912                    // padded sat bf16: 8 x [h64][slot80][n16][c16]
#define SATP_SLICE_U16 (64*80*16*16)         // 1310720
#define OFF_GRDB_B (OFF_SATP_B + 8*SATP_SLICE_U16*2)   // 21266432
#define GRD_SLICE_U16 (64*64*16*16)          // 1048576
#define OFF_PART_B (OFF_GRDB_B + 8*GRD_SLICE_U16*2)    // 38043648
// part: per corr-block 2 chunks (dyi pair) x 17 x 256 floats = 8704 f

typedef __bf16 bf16x8 __attribute__((ext_vector_type(8)));
typedef float floatx4 __attribute__((ext_vector_type(4)));
typedef unsigned short ushort8 __attribute__((ext_vector_type(8)));

#define AS1 __attribute__((address_space(1)))
#define AS3 __attribute__((address_space(3)))

__device__ inline unsigned short f2bf(float f) {
    unsigned x = __float_as_uint(f);
    unsigned r = x + 0x7FFFu + ((x >> 16) & 1u);   // RNE
    return (unsigned short)(r >> 16);
}

// ---------------- K1: convert + transpose + norms/energy (coalesced) -----
// grid: 1024 = tensor2 x h64 x csl8
__global__ __launch_bounds__(256) void k_prep(const float* __restrict__ sat,
                                              const float* __restrict__ grd,
                                              float* __restrict__ ws) {
    __shared__ unsigned short tile[64 * 256];   // 32 KB: [w][ (n+w)&15 ][c16]
    int b = blockIdx.x;
    int tensor = b >> 9, h = (b >> 3) & 63, csl = b & 7;
    const float* src = tensor ? grd : sat;
    unsigned short* dstS = (unsigned short*)((char*)ws + OFF_SATP_B);
    unsigned short* dstG = (unsigned short*)((char*)ws + OFF_GRDB_B);
    int t = threadIdx.x;
    int n = t >> 4, wq = t & 15;

    float en0 = 0.f, en1 = 0.f, en2 = 0.f, en3 = 0.f;
    const float* base = src + ((size_t)(n * CCH + csl * 16) * 4096) + h * 64 + wq * 4;
    int w0 = wq * 4;
    #pragma unroll
    for (int c = 0; c < 16; ++c) {
        float4 v = *(const float4*)(base + (size_t)c * 4096);
        en0 = fmaf(v.x, v.x, en0); en1 = fmaf(v.y, v.y, en1);
        en2 = fmaf(v.z, v.z, en2); en3 = fmaf(v.w, v.w, en3);
        tile[(w0 + 0) * 256 + ((n + w0 + 0) & 15) * 16 + c] = f2bf(v.x);
        tile[(w0 + 1) * 256 + ((n + w0 + 1) & 15) * 16 + c] = f2bf(v.y);
        tile[(w0 + 2) * 256 + ((n + w0 + 2) & 15) * 16 + c] = f2bf(v.z);
        tile[(w0 + 3) * 256 + ((n + w0 + 3) & 15) * 16 + c] = f2bf(v.w);
    }

    if (tensor == 0) {
        float* eg = ws + OFF_ENERGY + ((size_t)n * 64 + h) * 64 + w0;
        atomicAdd(eg + 0, en0); atomicAdd(eg + 1, en1);
        atomicAdd(eg + 2, en2); atomicAdd(eg + 3, en3);
    } else {
        float s = en0 + en1 + en2 + en3;
        #pragma unroll
        for (int off = 8; off; off >>= 1) s += __shfl_xor(s, off);  // 16-lane group
        if (wq == 0) atomicAdd(&ws[OFF_NORM + n], s);
    }

    __syncthreads();
    unsigned short* dst = tensor
        ? dstG + (size_t)csl * GRD_SLICE_U16 + (size_t)h * 16384
        : dstS + (size_t)csl * SATP_SLICE_U16 + ((size_t)h * 80 + 8) * 256;
    #pragma unroll
    for (int i = 0; i < 8; ++i) {
        int o = i * 256 + t;
        int w = o >> 5, nn = (o >> 1) & 15, c8 = o & 1;
        ushort8 val = *(ushort8*)&tile[w * 256 + ((nn + w) & 15) * 16 + c8 * 8];
        *(ushort8*)&dst[(size_t)o * 8] = val;
    }
    if (tensor == 0) {
        ushort8 z = (ushort8)0;
        #pragma unroll
        for (int i = 0; i < 2; ++i) {
            int o = i * 256 + t;
            int slot = o >> 5, wi = o & 31;
            int ps = slot < 8 ? slot : slot + 64;
            *(ushort8*)&dstS[(size_t)csl * SATP_SLICE_U16 +
                             ((size_t)h * 80 + ps) * 256 + wi * 8] = z;
        }
    }
}

// ---------------- K2: windowed energy -> scale (separable, 1 block/m) ----
__global__ __launch_bounds__(320) void k_scale(float* __restrict__ ws) {
    __shared__ float E[64 * 64];
    __shared__ float R[64 * 17];
    int m = blockIdx.x;
    int t = threadIdx.x;
    const float* energy = ws + OFF_ENERGY + (size_t)m * 4096;
    float* scale = ws + OFF_SCALE + (size_t)m * NSHIFT;
    for (int i = t; i < 4096; i += 320) E[i] = energy[i];
    __syncthreads();
    for (int i = t; i < 64 * 17; i += 320) {
        int y = i / 17, j = i % 17;
        int x0 = max(0, j - 8), x1 = min(64, j + 56);
        float s = 0.f;
        for (int x = x0; x < x1; ++x) s += E[y * 64 + x];
        R[i] = s;
    }
    __syncthreads();
    for (int idx = t; idx < NSHIFT; idx += 320) {
        int ii = idx / 17, j = idx % 17;
        int y0 = max(0, ii - 8), y1 = min(64, ii + 56);
        float s = 0.f;
        for (int y = y0; y < y1; ++y) s += R[y * 17 + j];
        scale[idx] = 1.f / fmaxf(sqrtf(s), 1e-12f);
    }
}

// ---------------- K3: MFMA cross-correlation, dyi-PAIRED ------------------
// grid: 72*NS.  b: csl = b&7 (XCD low-bits), r2 = b>>3, p9 = r2%9 -> dyi pair
// (2p, 2p+1), strip = r2/9 -> h0 = strip*HS.  Each staged sat row hs serves
// BOTH dyi values (B rows h_hi = hs-d0+8 and h_hi-1) -> every ds_read_b128
// feeds 16 MFMAs, every barrier covers 1088 block-MFMAs (~5.3k cyc).
// acc: 2x17 floatx4 = 136 AGPR; 2 blocks/CU (launch_bounds(256,2) = 256 reg).
__global__ __launch_bounds__(256, 2) void k_corr(const unsigned short* __restrict__ satp,
                                                 const unsigned short* __restrict__ grdb,
                                                 float* __restrict__ part, int HS) {
    __shared__ alignas(16) unsigned char smem[81920];
    int b = blockIdx.x;
    int csl = b & 7;
    int r2  = b >> 3;
    int p9  = r2 % 9;
    int h0  = (r2 / 9) * HS;
    int d0  = 2 * p9;
    int t = threadIdx.x;
    int wv = t >> 6, l = t & 63;
    int m16 = l & 15, q = l >> 4, jl = q >> 1, c8 = q & 1;
    int wbase = wv * 16;

    const unsigned short* sats = satp + (size_t)csl * SATP_SLICE_U16;
    const unsigned short* grds = grdb + (size_t)csl * GRD_SLICE_U16;
    const unsigned short* goff = grds + ((wbase + jl) * 16 + m16) * 16 + c8 * 8;

    floatx4 acc0[17], acc1[17];
    #pragma unroll
    for (int d = 0; d < 17; ++d) { acc0[d] = (floatx4)0.f; acc1[d] = (floatx4)0.f; }

    #define STAGE(hs, p)                                                            \
        do {                                                                        \
            _Pragma("unroll")                                                       \
            for (int i_ = 0; i_ < 10; ++i_) {                                       \
                const unsigned short* g_ = sats + (size_t)(hs) * 20480              \
                                         + wv * 5120 + i_ * 512 + l * 8;            \
                __builtin_amdgcn_global_load_lds((AS1 void*)(unsigned short*)g_,    \
                    (AS3 void*)(smem + (p) * 40960 + wv * 10240 + i_ * 1024 + l * 16), \
                    16, 0, 0);                                                      \
            }                                                                       \
        } while (0)

    #define MFMA8(ACC, BB)                                                          \
        do {                                                                        \
            _Pragma("unroll")                                                       \
            for (int bi = 0; bi < 8; ++bi) {                                        \
                int dxi = wo - 2 * bi;                                              \
                if (dxi >= 0 && dxi <= 16)                                          \
                    ACC[dxi] = __builtin_amdgcn_mfma_f32_16x16x32_bf16(A, BB[bi], ACC[dxi], 0, 0, 0); \
            }                                                                       \
        } while (0)

    int hsA = max(0, h0 + d0 - 8);
    int hsB = min(63, h0 + HS + d0 - 8);
    if (hsA <= hsB) {
        STAGE(hsA, 0);
        for (int hs = hsA; hs <= hsB; ++hs) {
            int pbuf = (hs - hsA) & 1;
            __syncthreads();                       // staged buf ready
            if (hs < hsB) STAGE(hs + 1, pbuf ^ 1);
            int h_hi = hs - d0 + 8;
            bool v0 = (unsigned)(h_hi - h0) < (unsigned)HS;
            bool v1 = (d0 < 16) && ((unsigned)(h_hi - 1 - h0) < (unsigned)HS);
            if (v0 | v1) {
                int rhi = min(max(h_hi, 0), 63);
                int rlo = min(max(h_hi - 1, 0), 63);
                bf16x8 Bhi[8], Blo[8];
                #pragma unroll
                for (int bi = 0; bi < 8; ++bi) {
                    Bhi[bi] = *(const bf16x8*)(goff + (size_t)rhi * 16384 + bi * 512);
                    Blo[bi] = *(const bf16x8*)(goff + (size_t)rlo * 16384 + bi * 512);
                }
                const unsigned char* aptr = smem + pbuf * 40960 + jl * 512 + m16 * 32 + c8 * 16;
                #pragma unroll
                for (int wo = 0; wo < 31; ++wo) {
                    bf16x8 A = *(const bf16x8*)(aptr + (wbase + wo) * 512);
                    if (v0) { MFMA8(acc0, Bhi); }
                    if (v1) { MFMA8(acc1, Blo); }
                }
            }
        }
    }
    #undef STAGE
    #undef MFMA8

    // cross-wave reduce in LDS (reuse buffer 0), plain partial store
    __syncthreads();
    float* red = (float*)smem;        // 2 x 4352 floats = 34816 B
    for (int i = t; i < 2176; i += 256) ((floatx4*)red)[i] = (floatx4)0.f;
    __syncthreads();
    #pragma unroll
    for (int dxi = 0; dxi < 17; ++dxi) {
        #pragma unroll
        for (int r = 0; r < 4; ++r) {
            atomicAdd(&red[(r * 17 + dxi) * 64 + l], acc0[dxi][r]);
            atomicAdd(&red[4352 + (r * 17 + dxi) * 64 + l], acc1[dxi][r]);
        }
    }
    __syncthreads();
    float* pb = part + (size_t)b * 8704;
    for (int i = t; i < 2176; i += 256) ((floatx4*)pb)[i] = ((floatx4*)red)[i];
}

// ---------------- K4: reduce partials + scale + sim-max -------------------
__global__ void k_reduce(const float* __restrict__ part, float* __restrict__ ws, int NS) {
    int b = blockIdx.x;            // 289
    int dyi = b / 17, dxi = b % 17;
    int pp = dyi >> 1, e = dyi & 1;
    int t = threadIdx.x;
    int l = t & 63, r = t >> 6;
    size_t off = (size_t)e * 4352 + (r * 17 + dxi) * 64 + l;
    float s = 0.f;
    for (int strip = 0; strip < NS; ++strip) {
        #pragma unroll
        for (int csl = 0; csl < 8; ++csl) {
            int blk = ((strip * 9 + pp) << 3) | csl;
            s += part[(size_t)blk * 8704 + off];
        }
    }
    int n = l & 15, q = l >> 4, m = q * 4 + r;
    float val = s * ws[OFF_SCALE + m * NSHIFT + dyi * 17 + dxi];
    int iv = __float_as_int(val);
    unsigned key = (iv >= 0) ? ((unsigned)iv | 0x80000000u) : (unsigned)(~iv);
    atomicMax((unsigned*)ws + OFF_KEY + m * 16 + n, key);
}

// ---------------- K5: epilogue -> 3 scalars ----------------
__global__ void k_final(const float* __restrict__ ws, float* __restrict__ out) {
    const unsigned* keys = (const unsigned*)ws + OFF_KEY;
    const float* norms = ws + OFF_NORM;
    __shared__ float dist_s[256];
    __shared__ float pos_s[16];
    __shared__ float red[256];
    __shared__ float minv[16];
    int t = threadIdx.x;          // t = m*16 + n
    int m = t >> 4, n = t & 15;

    unsigned u = keys[t];
    int iv = (u & 0x80000000u) ? (int)(u & 0x7fffffffu) : ~(int)u;
    float best = __int_as_float(iv);
    float Ng  = sqrtf(norms[n]);
    float sim = best / fmaxf(Ng, 1e-12f);
    float d   = 2.f - 2.f * sim;
    dist_s[t] = d;
    if (m == n) pos_s[m] = d;
    __syncthreads();

    float x1 = (pos_s[n] - d) * 10.f;
    float x2 = (pos_s[m] - d) * 10.f;
    float sp1 = x1 > 20.f ? x1 : log1pf(expf(x1));
    float sp2 = x2 > 20.f ? x2 : log1pf(expf(x2));
    red[t] = sp1 + sp2;
    __syncthreads();
    for (int off = 128; off; off >>= 1) {
        if (t < off) red[t] += red[t + off];
        __syncthreads();
    }
    if (t < 16) {
        float mv = 1e30f;
        for (int nn = 0; nn < 16; ++nn) mv = fminf(mv, dist_s[t * 16 + nn]);
        minv[t] = mv;
    }
    __syncthreads();
    if (t == 0) {
        float psum = 0.f, msum = 0.f;
        for (int qq = 0; qq < 16; ++qq) { psum += pos_s[qq]; msum += minv[qq]; }
        out[0] = red[0] / 48.f;
        out[1] = psum / 16.f;
        out[2] = msum / 16.f;
    }
}

extern "C" void kernel_launch(void* const* d_in, const int* in_sizes, int n_in,
                              void* d_out, int out_size, void* d_ws, size_t ws_size,
                              hipStream_t stream) {
    const float* sat = (const float*)d_in[0];
    const float* grd = (const float*)d_in[1];
    float* out = (float*)d_out;
    float* ws  = (float*)d_ws;
    const unsigned short* satp = (const unsigned short*)((char*)d_ws + OFF_SATP_B);
    const unsigned short* grdb = (const unsigned short*)((char*)d_ws + OFF_GRDB_B);
    float* part = (float*)((char*)d_ws + OFF_PART_B);

    // ws-size-adaptive strip count (deterministic across calls)
    const size_t NEED16 = (size_t)OFF_PART_B + (size_t)1152 * 8704 * 4;
    int NS = (ws_size >= NEED16) ? 16 : 8;
    int HS = 64 / NS;

    hipMemsetAsync(d_ws, 0, ZERO_BYTES, stream);   // keys + norm + energy
    k_prep  <<<1024,    256, 0, stream>>>(sat, grd, ws);
    k_scale <<<16,      320, 0, stream>>>(ws);
    k_corr  <<<72 * NS, 256, 0, stream>>>(satp, grdb, part, HS);
    k_reduce<<<NSHIFT,  256, 0, stream>>>(part, ws, NS);
    k_final <<<1,       256, 0, stream>>>(ws, out);
}

// Round 9
// 214.656 us; speedup vs baseline: 2.0065x; 2.0065x over previous
//
#include <hip/hip_runtime.h>
#include <math.h>

#define CCH 128
#define HH 64
#define WW 64
#define SHD 17
#define NSHIFT (SHD*SHD)   // 289

// ---- workspace layout ----
// float-index offsets:
#define OFF_KEY    0                         // 256 u32 monotone sim-max keys
#define OFF_NPART  256                       // 512*16 f  grd-norm partials [(h*8+csl)][n]
#define OFF_EPART  8448                      // 8*65536 f energy partials [csl][(n*64+h)*64+w]
#define OFF_SCALE  532736                    // 16*289 f
// byte offsets:
#define OFF_SATP_B 2162688                   // padded sat bf16: 8 x [h64][slot80][n16][c16]
#define SATP_SLICE_U16 (64*80*16*16)         // 1310720
#define OFF_GRDB_B (OFF_SATP_B + 8*SATP_SLICE_U16*2)   // 23134208
#define GRD_SLICE_U16 (64*64*16*16)          // 1048576
#define OFF_PART_B (OFF_GRDB_B + 8*GRD_SLICE_U16*2)    // 39911424
#define NBLK_CORR 1088                       // csl8 (low bits) x dyi17 x hq8
// part: per (block,wave): 68 x 64 floats; total 1088*4*4352*4 B = 19 MB

typedef __bf16 bf16x8 __attribute__((ext_vector_type(8)));
typedef float floatx4 __attribute__((ext_vector_type(4)));
typedef unsigned short ushort8 __attribute__((ext_vector_type(8)));

#define AS1 __attribute__((address_space(1)))
#define AS3 __attribute__((address_space(3)))

__device__ inline unsigned short f2bf(float f) {
    unsigned x = __float_as_uint(f);
    unsigned r = x + 0x7FFFu + ((x >> 16) & 1u);   // RNE
    return (unsigned short)(r >> 16);
}

// ---------------- K1: convert + transpose + norm/energy partials ----------
// grid: 1024 = tensor2 x h64 x csl8.  No atomics, no pre-zero needed.
__global__ __launch_bounds__(256) void k_prep(const float* __restrict__ sat,
                                              const float* __restrict__ grd,
                                              float* __restrict__ ws) {
    __shared__ unsigned short tile[64 * 256];   // 32 KB: [w][ (n+w)&15 ][c16]
    __shared__ float nred[16];
    int b = blockIdx.x;
    int tensor = b >> 9, h = (b >> 3) & 63, csl = b & 7;
    const float* src = tensor ? grd : sat;
    unsigned short* dstS = (unsigned short*)((char*)ws + OFF_SATP_B);
    unsigned short* dstG = (unsigned short*)((char*)ws + OFF_GRDB_B);
    int t = threadIdx.x;
    int n = t >> 4, wq = t & 15;

    float en0 = 0.f, en1 = 0.f, en2 = 0.f, en3 = 0.f;
    const float* base = src + ((size_t)(n * CCH + csl * 16) * 4096) + h * 64 + wq * 4;
    int w0 = wq * 4;
    #pragma unroll
    for (int c = 0; c < 16; ++c) {
        float4 v = *(const float4*)(base + (size_t)c * 4096);
        en0 = fmaf(v.x, v.x, en0); en1 = fmaf(v.y, v.y, en1);
        en2 = fmaf(v.z, v.z, en2); en3 = fmaf(v.w, v.w, en3);
        tile[(w0 + 0) * 256 + ((n + w0 + 0) & 15) * 16 + c] = f2bf(v.x);
        tile[(w0 + 1) * 256 + ((n + w0 + 1) & 15) * 16 + c] = f2bf(v.y);
        tile[(w0 + 2) * 256 + ((n + w0 + 2) & 15) * 16 + c] = f2bf(v.z);
        tile[(w0 + 3) * 256 + ((n + w0 + 3) & 15) * 16 + c] = f2bf(v.w);
    }

    if (tensor == 0) {
        float* eg = ws + OFF_EPART + (size_t)csl * 65536 + ((size_t)n * 64 + h) * 64 + w0;
        *(float4*)eg = make_float4(en0, en1, en2, en3);   // plain partial store
    } else {
        float s = en0 + en1 + en2 + en3;
        #pragma unroll
        for (int off = 8; off; off >>= 1) s += __shfl_xor(s, off);  // 16-lane group
        if (wq == 0) nred[n] = s;
    }

    __syncthreads();
    if (tensor == 1 && t < 16)
        ws[OFF_NPART + (size_t)(h * 8 + csl) * 16 + t] = nred[t];

    unsigned short* dst = tensor
        ? dstG + (size_t)csl * GRD_SLICE_U16 + (size_t)h * 16384
        : dstS + (size_t)csl * SATP_SLICE_U16 + ((size_t)h * 80 + 8) * 256;
    #pragma unroll
    for (int i = 0; i < 8; ++i) {
        int o = i * 256 + t;
        int w = o >> 5, nn = (o >> 1) & 15, c8 = o & 1;
        ushort8 val = *(ushort8*)&tile[w * 256 + ((nn + w) & 15) * 16 + c8 * 8];
        *(ushort8*)&dst[(size_t)o * 8] = val;
    }
    if (tensor == 0) {
        ushort8 z = (ushort8)0;
        #pragma unroll
        for (int i = 0; i < 2; ++i) {
            int o = i * 256 + t;
            int slot = o >> 5, wi = o & 31;
            int ps = slot < 8 ? slot : slot + 64;
            *(ushort8*)&dstS[(size_t)csl * SATP_SLICE_U16 +
                             ((size_t)h * 80 + ps) * 256 + wi * 8] = z;
        }
    }
}

// ---------------- K2: energy partial-sum -> windowed scale; zero keys -----
__global__ __launch_bounds__(320) void k_scale(float* __restrict__ ws) {
    __shared__ float E[64 * 64];
    __shared__ float R[64 * 17];
    int m = blockIdx.x;
    int t = threadIdx.x;
    float* scale = ws + OFF_SCALE + (size_t)m * NSHIFT;
    if (t < 16) ((unsigned*)ws)[OFF_KEY + m * 16 + t] = 0u;   // zero sim-max keys
    const float* ep = ws + OFF_EPART + (size_t)m * 4096;
    for (int i = t; i < 4096; i += 320) {
        float s = 0.f;
        #pragma unroll
        for (int csl = 0; csl < 8; ++csl) s += ep[(size_t)csl * 65536 + i];
        E[i] = s;
    }
    __syncthreads();
    for (int i = t; i < 64 * 17; i += 320) {
        int y = i / 17, j = i % 17;
        int x0 = max(0, j - 8), x1 = min(64, j + 56);
        float s = 0.f;
        for (int x = x0; x < x1; ++x) s += E[y * 64 + x];
        R[i] = s;
    }
    __syncthreads();
    for (int idx = t; idx < NSHIFT; idx += 320) {
        int ii = idx / 17, j = idx % 17;
        int y0 = max(0, ii - 8), y1 = min(64, ii + 56);
        float s = 0.f;
        for (int y = y0; y < y1; ++y) s += R[y * 17 + j];
        scale[idx] = 1.f / fmaxf(sqrtf(s), 1e-12f);
    }
}

// ---------------- K3: MFMA cross-correlation (balanced, zero-sync epi) ----
// grid 1088: csl = b&7 (XCD low bits), dyi = (b>>3)%17, hq = (b>>3)/17,
// h0 = hq*8 (8-row strips -> 2x finer work granularity than R7; avg 8 staged
// rows/block, so tail imbalance shrinks). Double-buffered 40KB row stage via
// global_load_lds; B register-prefetched one row ahead; A software-pipelined
// one wo ahead. Epilogue: per-wave coalesced global partial stores, NO
// syncthreads, no LDS atomics.
__global__ __launch_bounds__(256, 2) void k_corr(const unsigned short* __restrict__ satp,
                                                 const unsigned short* __restrict__ grdb,
                                                 float* __restrict__ part) {
    __shared__ alignas(16) unsigned char smem[81920];
    int b = blockIdx.x;
    int csl = b & 7;
    int r2  = b >> 3;
    int dyi = r2 % 17;
    int hq  = r2 / 17;             // 0..7
    int h0  = hq * 8;
    int t = threadIdx.x;
    int wv = t >> 6, l = t & 63;
    int m16 = l & 15, q = l >> 4, jl = q >> 1, c8 = q & 1;
    int wbase = wv * 16;

    const unsigned short* sats = satp + (size_t)csl * SATP_SLICE_U16;
    const unsigned short* grds = grdb + (size_t)csl * GRD_SLICE_U16;
    const unsigned short* goff = grds + ((wbase + jl) * 16 + m16) * 16 + c8 * 8;
    int hl = max(0, 8 - dyi - h0), hu = min(8, 72 - dyi - h0);

    floatx4 acc[17];
    #pragma unroll
    for (int d = 0; d < 17; ++d) acc[d] = (floatx4)0.f;

    #define STAGE(hs, p)                                                            \
        do {                                                                        \
            _Pragma("unroll")                                                       \
            for (int i_ = 0; i_ < 10; ++i_) {                                       \
                const unsigned short* g_ = sats + (size_t)(hs) * 20480              \
                                         + wv * 5120 + i_ * 512 + l * 8;            \
                __builtin_amdgcn_global_load_lds((AS1 void*)(unsigned short*)g_,    \
                    (AS3 void*)(smem + (p) * 40960 + wv * 10240 + i_ * 1024 + l * 16), \
                    16, 0, 0);                                                      \
            }                                                                       \
        } while (0)

    if (hl < hu) {
        int hs0 = h0 + hl + dyi - 8;
        STAGE(hs0, 0);
        bf16x8 Bc[8], Bn[8];
        #pragma unroll
        for (int bi = 0; bi < 8; ++bi)
            Bc[bi] = *(const bf16x8*)(goff + (size_t)(h0 + hl) * 16384 + bi * 512);

        for (int hh = hl; hh < hu; ++hh) {
            __syncthreads();                     // staged buf[hh&1] ready
            int p = (hh - hl) & 1;
            if (hh + 1 < hu) {
                STAGE(hs0 + (hh - hl) + 1, p ^ 1);
                #pragma unroll
                for (int bi = 0; bi < 8; ++bi)
                    Bn[bi] = *(const bf16x8*)(goff + (size_t)(h0 + hh + 1) * 16384 + bi * 512);
            }
            const unsigned char* aptr = smem + p * 40960 + jl * 512 + m16 * 32 + c8 * 16;
            bf16x8 A = *(const bf16x8*)(aptr + wbase * 512);
            #pragma unroll
            for (int wo = 0; wo < 31; ++wo) {    // slot = wbase + wo (+jl)
                bf16x8 An = A;
                if (wo < 30) An = *(const bf16x8*)(aptr + (wbase + wo + 1) * 512);
                #pragma unroll
                for (int bi = 0; bi < 8; ++bi) {
                    int dxi = wo - 2 * bi;       // compile-time after unroll
                    if (dxi >= 0 && dxi <= 16)
                        acc[dxi] = __builtin_amdgcn_mfma_f32_16x16x32_bf16(A, Bc[bi], acc[dxi], 0, 0, 0);
                }
                A = An;
            }
            #pragma unroll
            for (int bi = 0; bi < 8; ++bi) Bc[bi] = Bn[bi];
        }
    }
    #undef STAGE

    // per-wave coalesced partial store (no cross-wave sync needed)
    float* pw = part + ((size_t)(b * 4 + wv) * 68) * 64;
    #pragma unroll
    for (int dxi = 0; dxi < 17; ++dxi)
        #pragma unroll
        for (int r = 0; r < 4; ++r)
            pw[(dxi * 4 + r) * 64 + l] = acc[dxi][r];
}

// ---------------- K4: reduce partials + scale + sim-max -------------------
__global__ void k_reduce(const float* __restrict__ part, float* __restrict__ ws) {
    int b = blockIdx.x;            // 289
    int dyi = b / 17, dxi = b % 17;
    int t = threadIdx.x;
    int l = t & 63, r = t >> 6;
    size_t eo = (size_t)(dxi * 4 + r) * 64 + l;
    float s = 0.f;
    for (int hq = 0; hq < 8; ++hq) {
        #pragma unroll
        for (int cw = 0; cw < 32; ++cw) {        // csl(8) x wv(4)
            int csl = cw >> 2, wvv = cw & 3;
            size_t blk = (size_t)((hq * 17 + dyi) * 8 + csl) * 4 + wvv;
            s += part[blk * 4352 + eo];
        }
    }
    int n = l & 15, q = l >> 4, m = q * 4 + r;
    float val = s * ws[OFF_SCALE + m * NSHIFT + dyi * 17 + dxi];
    int iv = __float_as_int(val);
    unsigned key = (iv >= 0) ? ((unsigned)iv | 0x80000000u) : (unsigned)(~iv);
    atomicMax((unsigned*)ws + OFF_KEY + m * 16 + n, key);
}

// ---------------- K5: epilogue -> 3 scalars ----------------
__global__ void k_final(const float* __restrict__ ws, float* __restrict__ out) {
    const unsigned* keys = (const unsigned*)ws + OFF_KEY;
    __shared__ float dist_s[256];
    __shared__ float pos_s[16];
    __shared__ float red[256];
    __shared__ float minv[16];
    __shared__ float norms_s[16];
    int t = threadIdx.x;          // t = m*16 + n
    int m = t >> 4, n = t & 15;

    if (t < 16) {                  // grd sumsq: sum 512 partials
        float s = 0.f;
        const float* np = ws + OFF_NPART + t;
        #pragma unroll 8
        for (int j = 0; j < 512; ++j) s += np[(size_t)j * 16];
        norms_s[t] = s;
    }
    __syncthreads();

    unsigned u = keys[t];
    int iv = (u & 0x80000000u) ? (int)(u & 0x7fffffffu) : ~(int)u;
    float best = __int_as_float(iv);
    float Ng  = sqrtf(norms_s[n]);
    float sim = best / fmaxf(Ng, 1e-12f);
    float d   = 2.f - 2.f * sim;
    dist_s[t] = d;
    if (m == n) pos_s[m] = d;
    __syncthreads();

    float x1 = (pos_s[n] - d) * 10.f;
    float x2 = (pos_s[m] - d) * 10.f;
    float sp1 = x1 > 20.f ? x1 : log1pf(expf(x1));
    float sp2 = x2 > 20.f ? x2 : log1pf(expf(x2));
    red[t] = sp1 + sp2;
    __syncthreads();
    for (int off = 128; off; off >>= 1) {
        if (t < off) red[t] += red[t + off];
        __syncthreads();
    }
    if (t < 16) {
        float mv = 1e30f;
        for (int nn = 0; nn < 16; ++nn) mv = fminf(mv, dist_s[t * 16 + nn]);
        minv[t] = mv;
    }
    __syncthreads();
    if (t == 0) {
        float psum = 0.f, msum = 0.f;
        for (int qq = 0; qq < 16; ++qq) { psum += pos_s[qq]; msum += minv[qq]; }
        out[0] = red[0] / 48.f;
        out[1] = psum / 16.f;
        out[2] = msum / 16.f;
    }
}

extern "C" void kernel_launch(void* const* d_in, const int* in_sizes, int n_in,
                              void* d_out, int out_size, void* d_ws, size_t ws_size,
                              hipStream_t stream) {
    const float* sat = (const float*)d_in[0];
    const float* grd = (const float*)d_in[1];
    float* out = (float*)d_out;
    float* ws  = (float*)d_ws;
    const unsigned short* satp = (const unsigned short*)((char*)d_ws + OFF_SATP_B);
    const unsigned short* grdb = (const unsigned short*)((char*)d_ws + OFF_GRDB_B);
    float* part = (float*)((char*)d_ws + OFF_PART_B);

    k_prep  <<<1024,      256, 0, stream>>>(sat, grd, ws);
    k_scale <<<16,        320, 0, stream>>>(ws);
    k_corr  <<<NBLK_CORR, 256, 0, stream>>>(satp, grdb, part);
    k_reduce<<<NSHIFT,    256, 0, stream>>>(part, ws);
    k_final <<<1,         256, 0, stream>>>(ws, out);
}